// Round 3
// baseline (127.210 us; speedup 1.0000x reference)
//
#include <hip/hip_runtime.h>
#include <math.h>

typedef _Float16 half8 __attribute__((ext_vector_type(8)));
typedef float floatx4 __attribute__((ext_vector_type(4)));

#define SQ3 1.7320508075688772f

// bw layout: [path(4)][t(8)][s(2)][lane(64)][elem(8)] _Float16  (32768 = 64 KiB)
// bw value = W2[k][col] * scale, k = s*32 + (lane>>4)*8 + elem,
// col = path*128 + t*16 + (lane&15), scale = 1/32 (sqrt3 folded into path C)
__global__ __launch_bounds__(256) void prep_w2(const float* __restrict__ W2,
                                               _Float16* __restrict__ bw) {
    int t = blockIdx.x * 256 + threadIdx.x;
    if (t >= 32768) return;
    int i    = t & 7;
    int l    = (t >> 3) & 63;
    int s    = (t >> 9) & 1;
    int tt   = (t >> 10) & 7;
    int path = t >> 13;
    int k   = s * 32 + (l >> 4) * 8 + i;
    int col = path * 128 + tt * 16 + (l & 15);
    float scale = 0.03125f * (path == 2 ? SQ3 : 1.0f);
    bw[t] = (_Float16)(W2[k * 512 + col] * scale);
}

__global__ __launch_bounds__(256) void edge_kernel(
    const float* __restrict__ x, const float* __restrict__ pos,
    const int* __restrict__ ei, const float* __restrict__ W1,
    const _Float16* __restrict__ bw, float* __restrict__ out,
    int E, int ntiles)
{
    __shared__ __align__(16) float4 sW1v[16];          // W1 as float4[16]
    __shared__ __align__(16) float4 s_geo[64];         // dx,dy,dz,len
    __shared__ int s_dst[64];
    __shared__ __align__(16) _Float16 s_xs[64][8];
    __shared__ __align__(16) _Float16 s_xv[64][24];
    __shared__ __align__(16) _Float16 s_hA[4][2][64][8];
    __shared__ __align__(16) _Float16 s_part[2][64][64];

    const int tid  = threadIdx.x;
    const int wave = tid >> 6;     // 0..3 == path A,B,C,D
    const int lane = tid & 63;

    if (tid < 16) sW1v[tid] = reinterpret_cast<const float4*>(W1)[tid];

    // register-resident B fragments for this wave's path (16 frags = 64 VGPR)
    half8 bfrag[8][2];
    {
        const half8* bsrc = (const half8*)bw;
        #pragma unroll
        for (int t = 0; t < 8; ++t)
            #pragma unroll
            for (int s = 0; s < 2; ++s)
                bfrag[t][s] = bsrc[(size_t)wave * 1024 + (t * 2 + s) * 64 + lane];
    }

    for (int tile = blockIdx.x; tile < ntiles; tile += gridDim.x) {
        const int ebase = tile * 64;
        __syncthreads();   // protect LDS from previous tile's readers

        // ===== stage A: gather features + geometry + h (all 256 threads) =====
        {
            // feature gather: 4 threads per edge, each covers 8 floats -> f16
            int eg_l = tid >> 2, q = tid & 3;
            int eg = ebase + eg_l;
            int ec = (eg < E) ? eg : (E - 1);
            int si = ei[ec];
            const float* xr = x + (size_t)si * 32 + q * 8;
            float4 va = *reinterpret_cast<const float4*>(xr);
            float4 vb = *reinterpret_cast<const float4*>(xr + 4);
            half8 hv;
            hv[0] = (_Float16)va.x; hv[1] = (_Float16)va.y;
            hv[2] = (_Float16)va.z; hv[3] = (_Float16)va.w;
            hv[4] = (_Float16)vb.x; hv[5] = (_Float16)vb.y;
            hv[6] = (_Float16)vb.z; hv[7] = (_Float16)vb.w;
            if (q == 0) *(half8*)&s_xs[eg_l][0] = hv;
            else        *(half8*)&s_xv[eg_l][(q - 1) * 8] = hv;
        }
        {
            // geometry (x4 redundant) + h A-fragment build
            int sub = tid >> 6;
            int l   = tid & 63;
            int el  = sub * 16 + (l & 15);
            int kg  = l >> 4;
            int eg  = ebase + el;
            int ec  = (eg < E) ? eg : (E - 1);
            int si = ei[ec];
            int di = ei[E + ec];
            float ex = pos[di * 3 + 0] - pos[si * 3 + 0];
            float ey = pos[di * 3 + 1] - pos[si * 3 + 1];
            float ez = pos[di * 3 + 2] - pos[si * 3 + 2];
            float len = sqrtf(ex * ex + ey * ey + ez * ez);
            len = fmaxf(len, 1e-8f);
            float inv = 1.0f / len;
            if (kg == 0) {
                s_geo[el] = make_float4(ex * inv, ey * inv, ez * inv, len);
                s_dst[el] = di;
            }
            #pragma unroll
            for (int s = 0; s < 2; ++s) {
                float4 w0 = sW1v[s * 8 + kg * 2 + 0];
                float4 w1 = sW1v[s * 8 + kg * 2 + 1];
                float ww[8] = {w0.x, w0.y, w0.z, w0.w, w1.x, w1.y, w1.z, w1.w};
                half8 ha;
                #pragma unroll
                for (int i = 0; i < 8; ++i) {
                    float z = len * ww[i];
                    ha[i] = (_Float16)(z / (1.0f + __expf(-z)));
                }
                *(half8*)&s_hA[sub][s][l][0] = ha;
            }
        }
        __syncthreads();

        // ===== stage B: 4 subtiles x 16 MFMA per wave + path epilogue =====
        const int wp  = lane & 15;
        const int er0 = (lane >> 4) * 4;
        #pragma unroll
        for (int sub = 0; sub < 4; ++sub) {
            half8 a0 = *(const half8*)&s_hA[sub][0][lane][0];
            half8 a1 = *(const half8*)&s_hA[sub][1][lane][0];
            floatx4 acc[8];
            #pragma unroll
            for (int t = 0; t < 8; ++t) {
                floatx4 z = {0.f, 0.f, 0.f, 0.f};
                z = __builtin_amdgcn_mfma_f32_16x16x32_f16(a0, bfrag[t][0], z, 0, 0, 0);
                acc[t] = __builtin_amdgcn_mfma_f32_16x16x32_f16(a1, bfrag[t][1], z, 0, 0, 0);
            }

            if (wave == 0) {                 // path A: ms = xs . wA
                #pragma unroll
                for (int r = 0; r < 4; ++r) {
                    int e = sub * 16 + er0 + r;
                    half8 xs = *(const half8*)&s_xs[e][0];
                    float m = 0.f;
                    #pragma unroll
                    for (int u = 0; u < 8; ++u) m += (float)xs[u] * acc[u][r];
                    s_part[0][e][wp] = (_Float16)m;
                }
            } else if (wave == 1) {          // path B: ms = (xv.dir) . wB
                #pragma unroll
                for (int r = 0; r < 4; ++r) {
                    int e = sub * 16 + er0 + r;
                    half8 v0 = *(const half8*)&s_xv[e][0];
                    half8 v1 = *(const half8*)&s_xv[e][8];
                    half8 v2 = *(const half8*)&s_xv[e][16];
                    float4 g = s_geo[e];
                    float xf[24];
                    #pragma unroll
                    for (int i = 0; i < 8; ++i) {
                        xf[i] = (float)v0[i]; xf[8 + i] = (float)v1[i];
                        xf[16 + i] = (float)v2[i];
                    }
                    float m = 0.f;
                    #pragma unroll
                    for (int u = 0; u < 8; ++u) {
                        float dot = xf[u*3+0]*g.x + xf[u*3+1]*g.y + xf[u*3+2]*g.z;
                        m += dot * acc[u][r];
                    }
                    s_part[1][e][wp] = (_Float16)m;
                }
            } else if (wave == 2) {          // path C: mv = (xs.wC) * sqrt3*dir
                #pragma unroll
                for (int r = 0; r < 4; ++r) {
                    int e = sub * 16 + er0 + r;
                    half8 xs = *(const half8*)&s_xs[e][0];
                    float4 g = s_geo[e];
                    float cw = 0.f;
                    #pragma unroll
                    for (int u = 0; u < 8; ++u) cw += (float)xs[u] * acc[u][r];
                    s_part[0][e][16 + wp * 3 + 0] = (_Float16)(cw * g.x);
                    s_part[0][e][16 + wp * 3 + 1] = (_Float16)(cw * g.y);
                    s_part[0][e][16 + wp * 3 + 2] = (_Float16)(cw * g.z);
                }
            } else {                         // path D: mv = xv . wD
                #pragma unroll
                for (int r = 0; r < 4; ++r) {
                    int e = sub * 16 + er0 + r;
                    half8 v0 = *(const half8*)&s_xv[e][0];
                    half8 v1 = *(const half8*)&s_xv[e][8];
                    half8 v2 = *(const half8*)&s_xv[e][16];
                    float xf[24];
                    #pragma unroll
                    for (int i = 0; i < 8; ++i) {
                        xf[i] = (float)v0[i]; xf[8 + i] = (float)v1[i];
                        xf[16 + i] = (float)v2[i];
                    }
                    float m0 = 0.f, m1 = 0.f, m2 = 0.f;
                    #pragma unroll
                    for (int u = 0; u < 8; ++u) {
                        float w = acc[u][r];
                        m0 += xf[u*3+0] * w;
                        m1 += xf[u*3+1] * w;
                        m2 += xf[u*3+2] * w;
                    }
                    s_part[1][e][16 + wp * 3 + 0] = (_Float16)m0;
                    s_part[1][e][16 + wp * 3 + 1] = (_Float16)m1;
                    s_part[1][e][16 + wp * 3 + 2] = (_Float16)m2;
                }
            }
        }
        __syncthreads();

        // ===== stage C: coalesced atomic scatter, 64 edges =====
        {
            int c = tid & 63;
            int g = tid >> 6;
            #pragma unroll
            for (int k = 0; k < 16; ++k) {
                int e  = g * 16 + k;
                int eg = ebase + e;
                if (eg < E) {
                    float v = (float)s_part[0][e][c] + (float)s_part[1][e][c];
                    atomicAdd(out + (size_t)s_dst[e] * 64 + c, v);
                }
            }
        }
    }
}

__global__ __launch_bounds__(256) void node_kernel(
    float* __restrict__ out, const float* __restrict__ Ws,
    const float* __restrict__ Wns, const float* __restrict__ Wg, int N)
{
    int n = blockIdx.x * 256 + threadIdx.x;
    if (n >= N) return;
    float* row = out + (size_t)n * 64;

    float os[16], ov[48];
    #pragma unroll
    for (int q = 0; q < 4; ++q) {
        float4 v = *reinterpret_cast<const float4*>(row + q * 4);
        os[q*4+0]=v.x; os[q*4+1]=v.y; os[q*4+2]=v.z; os[q*4+3]=v.w;
    }
    #pragma unroll
    for (int q = 0; q < 12; ++q) {
        float4 v = *reinterpret_cast<const float4*>(row + 16 + q * 4);
        ov[q*4+0]=v.x; ov[q*4+1]=v.y; ov[q*4+2]=v.z; ov[q*4+3]=v.w;
    }

    float sres[16], gres[16];
    #pragma unroll
    for (int w = 0; w < 16; ++w) {
        float a = 0.f, b = 0.f;
        #pragma unroll
        for (int u = 0; u < 16; ++u) {
            float o_u = os[u];
            a += o_u * Ws[u * 16 + w];
            b += o_u * Wg[u * 16 + w];
        }
        a *= 0.25f; b *= 0.25f;
        sres[w] = a / (1.0f + __expf(-a));
        gres[w] = 1.0f / (1.0f + __expf(-b));
    }

    float gated[48];
    #pragma unroll
    for (int w = 0; w < 16; ++w) {
        float n0 = 0.f, n1 = 0.f, n2 = 0.f;
        #pragma unroll
        for (int u = 0; u < 16; ++u) {
            float wn = Wns[u * 16 + w];
            n0 += ov[u*3+0] * wn;
            n1 += ov[u*3+1] * wn;
            n2 += ov[u*3+2] * wn;
        }
        float gw = gres[w] * 0.25f;
        gated[w*3+0] = n0 * gw;
        gated[w*3+1] = n1 * gw;
        gated[w*3+2] = n2 * gw;
    }

    #pragma unroll
    for (int q = 0; q < 4; ++q) {
        float4 v = make_float4(sres[q*4+0], sres[q*4+1], sres[q*4+2], sres[q*4+3]);
        *reinterpret_cast<float4*>(row + q * 4) = v;
    }
    #pragma unroll
    for (int q = 0; q < 12; ++q) {
        float4 v = make_float4(gated[q*4+0], gated[q*4+1], gated[q*4+2], gated[q*4+3]);
        *reinterpret_cast<float4*>(row + 16 + q * 4) = v;
    }
}

extern "C" void kernel_launch(void* const* d_in, const int* in_sizes, int n_in,
                              void* d_out, int out_size, void* d_ws, size_t ws_size,
                              hipStream_t stream) {
    const float* x   = (const float*)d_in[0];
    const float* pos = (const float*)d_in[1];
    const int*   ei  = (const int*)d_in[2];
    const float* W1  = (const float*)d_in[3];
    const float* W2  = (const float*)d_in[4];
    const float* Ws  = (const float*)d_in[5];
    const float* Wns = (const float*)d_in[6];
    const float* Wg  = (const float*)d_in[7];

    int N = in_sizes[0] / 32;
    int E = in_sizes[2] / 2;
    int ntiles = (E + 63) / 64;
    float* out = (float*)d_out;
    _Float16* bw = (_Float16*)d_ws;

    hipMemsetAsync(d_out, 0, (size_t)N * 64 * sizeof(float), stream);
    prep_w2<<<128, 256, 0, stream>>>(W2, bw);
    int nblk = ntiles < 1280 ? ntiles : 1280;
    edge_kernel<<<nblk, 256, 0, stream>>>(x, pos, ei, W1, bw, out, E, ntiles);
    node_kernel<<<(N + 255) / 256, 256, 0, stream>>>(out, Ws, Wns, Wg, N);
}